// Round 9
// baseline (275.992 us; speedup 1.0000x reference)
//
#include <hip/hip_runtime.h>

#define B 2
#define HW 16384
#define PADW 130
#define OUTC 256
#define M_ROWS 8192  // B*64*64
#define MAXP 32      // max points/cell tracked (lambda=1 Poisson; P(>32) ~ 0)

typedef short s16x8 __attribute__((ext_vector_type(8)));
typedef float f32x4 __attribute__((ext_vector_type(4)));

__device__ __forceinline__ unsigned short f2bf(float f) {
    union { float f; unsigned int u; } v; v.f = f;
    unsigned int u = v.u;
    return (unsigned short)((u + 0x7fffu + ((u >> 16) & 1u)) >> 16);
}
__device__ __forceinline__ float bf2f(unsigned short h) {
    union { unsigned int u; float f; } v; v.u = ((unsigned int)h) << 16;
    return v.f;
}

// async global->LDS, 16B per lane; LDS dest = wave-uniform base + lane*16
__device__ __forceinline__ void gl_lds16(const void* g, void* l) {
    __builtin_amdgcn_global_load_lds(
        (const __attribute__((address_space(1))) unsigned int*)g,
        (__attribute__((address_space(3))) unsigned int*)l, 16, 0, 0);
}

__device__ __forceinline__ void cell_of(const float* __restrict__ loc, int r, int& ix, int& iy) {
    float lx = loc[r * 2 + 0];
    float ly = loc[r * 2 + 1];
    lx = fminf(fmaxf(lx, -1.f), 1.f);
    ly = fminf(fmaxf(ly, -1.f), 1.f);
    ix = min(max((int)rintf(((lx + 1.f) * 0.5f) * 127.f), 0), 127);
    iy = min(max((int)rintf(((ly + 1.f) * 0.5f) * 127.f), 0), 127);
}

// Build per-cell token lists, all 4 branches. One thread per point (131072 total).
__global__ void fill_k(const float* __restrict__ l0, const float* __restrict__ l1,
                       const float* __restrict__ l2, const float* __restrict__ l3,
                       const int* __restrict__ i0, const int* __restrict__ i1,
                       const int* __restrict__ i2, const int* __restrict__ i3,
                       int* __restrict__ cnt32, unsigned short* __restrict__ list) {
    int p = blockIdx.x * 256 + threadIdx.x;
    int j = p >> 15, r = p & 32767;
    const float* loc = j == 0 ? l0 : j == 1 ? l1 : j == 2 ? l2 : l3;
    const int* idx = j == 0 ? i0 : j == 1 ? i1 : j == 2 ? i2 : i3;
    int ix, iy;
    cell_of(loc, r, ix, iy);
    int cidx = (((j << 1) + (r >> 14)) << 14) + iy * 128 + ix;
    int pos = atomicAdd(&cnt32[cidx], 1);
    if (pos < MAXP) list[cidx * MAXP + pos] = (unsigned short)idx[r];
}

// Merged prep: gather j0/j1 padded maps (blocks < 3169) + weight/x conversions (rest).
__global__ void prep2_k(const float* __restrict__ x0, const float* __restrict__ x1,
                        const int* __restrict__ cnt32, const unsigned short* __restrict__ list,
                        unsigned short* __restrict__ mapB01,
                        const float* __restrict__ w0, const float* __restrict__ w1,
                        const float* __restrict__ w2, const float* __restrict__ w3,
                        unsigned short* __restrict__ wt01,
                        unsigned short* __restrict__ wtg2, unsigned short* __restrict__ wtg3,
                        const float* __restrict__ x2, const float* __restrict__ x3,
                        unsigned short* __restrict__ xb2, unsigned short* __restrict__ xb3) {
    if (blockIdx.x >= 3169) {
        int e = (blockIdx.x - 3169) * 256 + threadIdx.x;
        if (e < 442368) {
            // direct-conv weights j0/j1: [co][(kh*3+kw)*C + ci]
            int j = e < 147456 ? 0 : 1;
            int local = j ? e - 147456 : e;
            const float* w = j ? w1 : w0;
            int lc = 6 + j, C = 1 << lc;
            int ci = local & (C - 1);
            int rest = local >> lc;
            int seg = rest % 9, co = rest / 9;
            int kh = seg / 3, kw = seg % 3;
            wt01[e] = f2bf(w[(((co * C) + ci) * 3 + kh) * 3 + kw]);
        } else if (e < 2211840) {
            // GEMM-B weights j2/j3: row (kk*256+co), col ci  -> [2304][C]
            int j = e < 1032192 ? 2 : 3;
            int local = j == 2 ? e - 442368 : e - 1032192;
            const float* w = j == 2 ? w2 : w3;
            int lc = 6 + j, C = 1 << lc;
            int ci = local & (C - 1);
            int nrow = local >> lc;
            int kk = nrow >> 8, co = nrow & 255;
            int kh = kk / 3, kw = kk % 3;
            unsigned short* dst = j == 2 ? wtg2 : wtg3;
            dst[local] = f2bf(w[(((co * C) + ci) * 3 + kh) * 3 + kw]);
        } else if (e < 2736128) {
            xb2[e - 2211840] = f2bf(x2[e - 2211840]);
        } else {
            xb3[e - 2736128] = f2bf(x3[e - 2736128]);
        }
        return;
    }
    // ---- gather j0/j1: wave-sliced cells, lanes_per_cell = C/8, 8 ch/lane (16B store)
    int W = (blockIdx.x * 256 + threadIdx.x) >> 6;
    if (W >= 12675) return;
    int lane = threadIdx.x & 63;
    int j = (W < 4225) ? 0 : 1;
    int base = j ? 4225 : 0;
    const float* x = j ? x1 : x0;
    const int C = 64 << j;
    const int ntok = 16384 >> (2 * j);
    int u = W - base;
    int cellLocal = (u << (3 - j)) + (lane >> (3 + j));  // < 33800
    int sub = lane & ((8 << j) - 1);
    int ch0 = sub * 8;
    int b = cellLocal / 16900;
    int cc = cellLocal - b * 16900;
    int py = cc / 130, px = cc - py * 130;
    unsigned short* dst = mapB01 + (size_t)33800 * (C - 64) + (size_t)cellLocal * C + ch0;
    float a0 = 0.f, a1 = 0.f, a2 = 0.f, a3 = 0.f, a4 = 0.f, a5 = 0.f, a6 = 0.f, a7 = 0.f;
    if (py >= 1 && py <= 128 && px >= 1 && px <= 128) {
        int cidx = (((j << 1) + b) << 14) + (py - 1) * 128 + (px - 1);
        int n = cnt32[cidx];
        float inv = 1.0f / ((float)n + 1e-6f);
        int nn = min(n, MAXP);
        const unsigned short* lst = list + (size_t)cidx * MAXP;
        for (int p = 0; p < nn; p++) {
            int tok = lst[p];
            const float* xr = x + ((size_t)b * ntok + tok) * C + ch0;
            float4 v0 = *(const float4*)xr;
            float4 v1 = *(const float4*)(xr + 4);
            a0 += v0.x; a1 += v0.y; a2 += v0.z; a3 += v0.w;
            a4 += v1.x; a5 += v1.y; a6 += v1.z; a7 += v1.w;
        }
        a0 *= inv; a1 *= inv; a2 *= inv; a3 *= inv;
        a4 *= inv; a5 *= inv; a6 *= inv; a7 *= inv;
    }
    uint4 o;
    o.x = (unsigned int)f2bf(a0) | ((unsigned int)f2bf(a1) << 16);
    o.y = (unsigned int)f2bf(a2) | ((unsigned int)f2bf(a3) << 16);
    o.z = (unsigned int)f2bf(a4) | ((unsigned int)f2bf(a5) << 16);
    o.w = (unsigned int)f2bf(a6) | ((unsigned int)f2bf(a7) << 16);
    *(uint4*)dst = o;
}

// Unified MFMA dispatch: j1 direct conv (128 blk, 36 steps), j3 token-GEMM (72 blk, 16),
// j2 token-GEMM (288 blk, 8), j0 direct conv (128 blk, 18). 128x128 tiles, 2x2 waves of
// 64x64, double-buffered LDS DMA staging (r5-proven). Conv blocks fuse exact BN stats.
__global__ __launch_bounds__(256) void mm_k(const unsigned short* __restrict__ mapB01,
                                            const unsigned short* __restrict__ wt01,
                                            const unsigned short* __restrict__ xb2,
                                            const unsigned short* __restrict__ xb3,
                                            const unsigned short* __restrict__ wtg2,
                                            const unsigned short* __restrict__ wtg3,
                                            unsigned short* __restrict__ T2,
                                            unsigned short* __restrict__ T3,
                                            unsigned short* __restrict__ ybr,
                                            float* __restrict__ branchAcc) {
    __shared__ unsigned short As[2][128][32];
    __shared__ unsigned short Bs[2][128][32];
    __shared__ float red_s[4][64], red_ss[4][64];
    const int t = threadIdx.x;
    const int lane = t & 63;
    const int w = t >> 6;
    const int wm = w >> 1, wn = w & 1;
    const int bx = blockIdx.x;

    bool isconv;
    int j, mt, nt, K, steps, C, bgem = 0;
    const unsigned short *Abase, *Bbase;
    if (bx < 128) {  // j1 conv, longest first
        isconv = true; j = 1; mt = bx & 63; nt = (bx >> 6) & 1;
        C = 128; K = 9 * C; steps = 36;
        Abase = mapB01 + (size_t)33800 * 64;
        Bbase = wt01 + (size_t)2304 * 64;
    } else if (bx < 200) {  // j3 GEMM
        isconv = false; j = 3; int r = bx - 128;
        bgem = r / 36; r %= 36; mt = r / 18; nt = r % 18;
        C = 512; K = C; steps = 16;
        Abase = xb3 + (size_t)bgem * 256 * 512;
        Bbase = wtg3;
    } else if (bx < 488) {  // j2 GEMM
        isconv = false; j = 2; int r = bx - 200;
        bgem = r / 144; r %= 144; mt = r / 18; nt = r % 18;
        C = 256; K = C; steps = 8;
        Abase = xb2 + (size_t)bgem * 1024 * 256;
        Bbase = wtg2;
    } else {  // j0 conv
        isconv = true; j = 0; int r = bx - 488; mt = r & 63; nt = (r >> 6) & 1;
        C = 64; K = 9 * C; steps = 18;
        Abase = mapB01;
        Bbase = wt01;
    }

    // staging sources: lane -> (row lr, 16B quarter lq); 2 A rows + 2 B rows per lane
    const int lr = lane >> 2, lq = lane & 3;
    const unsigned short* pA[2];
    const unsigned short* pB[2];
#pragma unroll
    for (int i = 0; i < 2; i++) {
        int r = w * 32 + i * 16 + lr;
        if (isconv) {
            int s = mt * 128 + r;
            int bb = s >> 12, rem = s & 4095, oh = rem >> 6, ow = rem & 63;
            pA[i] = Abase + (size_t)((bb * PADW + 2 * oh) * PADW + 2 * ow) * C + lq * 8;
        } else {
            pA[i] = Abase + (size_t)(mt * 128 + r) * K + lq * 8;
        }
        pB[i] = Bbase + (size_t)(nt * 128 + r) * K + lq * 8;
    }

    int ci0 = 0, kwv = 0, offA = 0, offB = 0;
    gl_lds16(pA[0], &As[0][w * 32][0]);
    gl_lds16(pA[1], &As[0][w * 32 + 16][0]);
    gl_lds16(pB[0], &Bs[0][w * 32][0]);
    gl_lds16(pB[1], &Bs[0][w * 32 + 16][0]);

    f32x4 acc[4][4];
#pragma unroll
    for (int mi = 0; mi < 4; mi++)
#pragma unroll
        for (int ni = 0; ni < 4; ni++) acc[mi][ni] = (f32x4){0.f, 0.f, 0.f, 0.f};

    const int r16 = lane & 15, kg = lane >> 4;
    int buf = 0;
    for (int s = 0; s < steps; s++) {
        offB += 32;
        if (isconv) {
            ci0 += 32; offA += 32;
            if (ci0 == C) {
                ci0 = 0; kwv++;
                if (kwv == 3) { kwv = 0; offA += (PADW - 3) * C; }
            }
        } else {
            offA += 32;
        }
        __syncthreads();  // drains prior prefetch (issued a full phase ago)
        if (s + 1 < steps) {
            int nb = buf ^ 1;
            gl_lds16(pA[0] + offA, &As[nb][w * 32][0]);
            gl_lds16(pA[1] + offA, &As[nb][w * 32 + 16][0]);
            gl_lds16(pB[0] + offB, &Bs[nb][w * 32][0]);
            gl_lds16(pB[1] + offB, &Bs[nb][w * 32 + 16][0]);
        }
        s16x8 a0 = *(const s16x8*)&As[buf][wm * 64 + 0 * 16 + r16][kg * 8];
        s16x8 a1 = *(const s16x8*)&As[buf][wm * 64 + 1 * 16 + r16][kg * 8];
        s16x8 a2 = *(const s16x8*)&As[buf][wm * 64 + 2 * 16 + r16][kg * 8];
        s16x8 a3 = *(const s16x8*)&As[buf][wm * 64 + 3 * 16 + r16][kg * 8];
        s16x8 b0 = *(const s16x8*)&Bs[buf][wn * 64 + 0 * 16 + r16][kg * 8];
        s16x8 b1 = *(const s16x8*)&Bs[buf][wn * 64 + 1 * 16 + r16][kg * 8];
        s16x8 b2 = *(const s16x8*)&Bs[buf][wn * 64 + 2 * 16 + r16][kg * 8];
        s16x8 b3 = *(const s16x8*)&Bs[buf][wn * 64 + 3 * 16 + r16][kg * 8];
        acc[0][0] = __builtin_amdgcn_mfma_f32_16x16x32_bf16(a0, b0, acc[0][0], 0, 0, 0);
        acc[0][1] = __builtin_amdgcn_mfma_f32_16x16x32_bf16(a0, b1, acc[0][1], 0, 0, 0);
        acc[0][2] = __builtin_amdgcn_mfma_f32_16x16x32_bf16(a0, b2, acc[0][2], 0, 0, 0);
        acc[0][3] = __builtin_amdgcn_mfma_f32_16x16x32_bf16(a0, b3, acc[0][3], 0, 0, 0);
        acc[1][0] = __builtin_amdgcn_mfma_f32_16x16x32_bf16(a1, b0, acc[1][0], 0, 0, 0);
        acc[1][1] = __builtin_amdgcn_mfma_f32_16x16x32_bf16(a1, b1, acc[1][1], 0, 0, 0);
        acc[1][2] = __builtin_amdgcn_mfma_f32_16x16x32_bf16(a1, b2, acc[1][2], 0, 0, 0);
        acc[1][3] = __builtin_amdgcn_mfma_f32_16x16x32_bf16(a1, b3, acc[1][3], 0, 0, 0);
        acc[2][0] = __builtin_amdgcn_mfma_f32_16x16x32_bf16(a2, b0, acc[2][0], 0, 0, 0);
        acc[2][1] = __builtin_amdgcn_mfma_f32_16x16x32_bf16(a2, b1, acc[2][1], 0, 0, 0);
        acc[2][2] = __builtin_amdgcn_mfma_f32_16x16x32_bf16(a2, b2, acc[2][2], 0, 0, 0);
        acc[2][3] = __builtin_amdgcn_mfma_f32_16x16x32_bf16(a2, b3, acc[2][3], 0, 0, 0);
        acc[3][0] = __builtin_amdgcn_mfma_f32_16x16x32_bf16(a3, b0, acc[3][0], 0, 0, 0);
        acc[3][1] = __builtin_amdgcn_mfma_f32_16x16x32_bf16(a3, b1, acc[3][1], 0, 0, 0);
        acc[3][2] = __builtin_amdgcn_mfma_f32_16x16x32_bf16(a3, b2, acc[3][2], 0, 0, 0);
        acc[3][3] = __builtin_amdgcn_mfma_f32_16x16x32_bf16(a3, b3, acc[3][3], 0, 0, 0);
        buf ^= 1;
    }

    // C/D layout: col = lane&15, row = (lane>>4)*4 + reg
    const int rg = lane >> 4, c16 = lane & 15;
    if (!isconv) {
        unsigned short* T = (j == 3) ? T3 + (size_t)bgem * 256 * 2304
                                     : T2 + (size_t)bgem * 1024 * 2304;
#pragma unroll
        for (int mi = 0; mi < 4; mi++)
#pragma unroll
            for (int ni = 0; ni < 4; ni++)
#pragma unroll
                for (int reg = 0; reg < 4; reg++) {
                    int row = mt * 128 + wm * 64 + mi * 16 + rg * 4 + reg;
                    int col = nt * 128 + wn * 64 + ni * 16 + c16;
                    T[(size_t)row * 2304 + col] = f2bf(acc[mi][ni][reg]);
                }
    } else {
#pragma unroll
        for (int mi = 0; mi < 4; mi++)
#pragma unroll
            for (int ni = 0; ni < 4; ni++)
#pragma unroll
                for (int reg = 0; reg < 4; reg++) {
                    int row = mt * 128 + wm * 64 + mi * 16 + rg * 4 + reg;
                    int col = nt * 128 + wn * 64 + ni * 16 + c16;
                    ybr[((size_t)j * M_ROWS + row) * OUTC + col] = f2bf(acc[mi][ni][reg]);
                }
        // fused exact channel stats (unsplit K -> each value computed once)
#pragma unroll
        for (int ni = 0; ni < 4; ni++) {
            float s = 0.f, ss = 0.f;
#pragma unroll
            for (int mi = 0; mi < 4; mi++)
#pragma unroll
                for (int reg = 0; reg < 4; reg++) {
                    float v = acc[mi][ni][reg];
                    s += v;
                    ss += v * v;
                }
            s += __shfl_xor(s, 16, 64);
            ss += __shfl_xor(ss, 16, 64);
            s += __shfl_xor(s, 32, 64);
            ss += __shfl_xor(ss, 32, 64);
            if (rg == 0) {
                red_s[w][ni * 16 + c16] = s;
                red_ss[w][ni * 16 + c16] = ss;
            }
        }
        __syncthreads();
        if (t < 128) {
            int col = t;
            int cwn = col >> 6, rem = col & 63;
            float s = red_s[cwn][rem] + red_s[cwn + 2][rem];
            float ss = red_ss[cwn][rem] + red_ss[cwn + 2][rem];
            int ch = nt * 128 + col;
            atomicAdd(&branchAcc[j * 512 + ch], s);
            atomicAdd(&branchAcc[j * 512 + 256 + ch], ss);
        }
    }
}

// Assemble j2/j3 outputs from token-GEMM T via tap gather; fused exact stats.
// 256 blocks x 32 rows (4 waves x 8 rows); lane owns 4 channels (ch = lane*4+k).
__global__ __launch_bounds__(256) void asm_k(const int* __restrict__ cnt32,
                                             const unsigned short* __restrict__ list,
                                             const unsigned short* __restrict__ T2,
                                             const unsigned short* __restrict__ T3,
                                             unsigned short* __restrict__ ybr,
                                             float* __restrict__ branchAcc) {
    __shared__ float red[4][256];
    int t = threadIdx.x, lane = t & 63, w = t >> 6;
    int bi = blockIdx.x;
    int ch4 = lane << 2;
    float sreg[2][4], ssreg[2][4];
#pragma unroll
    for (int jj = 0; jj < 2; jj++)
#pragma unroll
        for (int k = 0; k < 4; k++) { sreg[jj][k] = 0.f; ssreg[jj][k] = 0.f; }

    for (int it = 0; it < 8; it++) {
        int srow = bi * 32 + w * 8 + it;
        int b = srow >> 12, rem = srow & 4095, oh = rem >> 6, ow = rem & 63;
#pragma unroll
        for (int jj = 0; jj < 2; jj++) {
            int j = 2 + jj;
            int nj = jj ? 256 : 1024;
            const unsigned short* T = jj ? T3 : T2;
            float a0 = 0.f, a1 = 0.f, a2 = 0.f, a3 = 0.f;
            for (int kh = 0; kh < 3; kh++) {
                int iy = 2 * oh + kh - 1;
                if ((unsigned)iy >= 128u) continue;
                for (int kw = 0; kw < 3; kw++) {
                    int ix = 2 * ow + kw - 1;
                    if ((unsigned)ix >= 128u) continue;
                    int cidx = (((j << 1) + b) << 14) + iy * 128 + ix;
                    int n = cnt32[cidx];
                    if (n == 0) continue;
                    float wc = 1.0f / ((float)n + 1e-6f);
                    int nn = min(n, MAXP);
                    const unsigned short* lst = list + (size_t)cidx * MAXP;
                    float t0 = 0.f, t1 = 0.f, t2 = 0.f, t3 = 0.f;
                    for (int p = 0; p < nn; p++) {
                        int tok = lst[p];
                        const unsigned short* Tp =
                            T + ((size_t)(b * nj + tok) * 2304 + (kh * 3 + kw) * 256 + ch4);
                        ushort4 u = *(const ushort4*)Tp;
                        t0 += bf2f(u.x);
                        t1 += bf2f(u.y);
                        t2 += bf2f(u.z);
                        t3 += bf2f(u.w);
                    }
                    a0 += wc * t0; a1 += wc * t1; a2 += wc * t2; a3 += wc * t3;
                }
            }
            ushort4 o;
            o.x = f2bf(a0); o.y = f2bf(a1); o.z = f2bf(a2); o.w = f2bf(a3);
            *(ushort4*)(ybr + ((size_t)j * M_ROWS + srow) * OUTC + ch4) = o;
            sreg[jj][0] += a0; sreg[jj][1] += a1; sreg[jj][2] += a2; sreg[jj][3] += a3;
            ssreg[jj][0] += a0 * a0; ssreg[jj][1] += a1 * a1;
            ssreg[jj][2] += a2 * a2; ssreg[jj][3] += a3 * a3;
        }
    }
    // block reduce: 4 passes (s2, ss2, s3, ss3)
    for (int pass = 0; pass < 4; pass++) {
        const float* src = (pass == 0) ? sreg[0] : (pass == 1) ? ssreg[0]
                            : (pass == 2) ? sreg[1] : ssreg[1];
#pragma unroll
        for (int k = 0; k < 4; k++) red[w][ch4 + k] = src[k];
        __syncthreads();
        float S = red[0][t] + red[1][t] + red[2][t] + red[3][t];
        __syncthreads();
        int jb = (pass >> 1) ? 3 : 2;
        atomicAdd(&branchAcc[jb * 512 + (pass & 1) * 256 + t], S);
    }
}

// fused: inline BN-fold from branchAcc + affine + 4-branch sum + NHWC->NCHW transpose
__global__ void out_k(const unsigned short* __restrict__ ybr, const float* __restrict__ branchAcc,
                      const float* __restrict__ g0, const float* __restrict__ g1,
                      const float* __restrict__ g2, const float* __restrict__ g3,
                      const float* __restrict__ b0, const float* __restrict__ b1,
                      const float* __restrict__ b2, const float* __restrict__ b3,
                      float* __restrict__ out) {
    __shared__ float tile[64][132];
    int oh = blockIdx.x, ct = blockIdx.y, b = blockIdx.z;  // 64, 2, 2
    int t = threadIdx.x;
    int cg = t & 31, rt = t >> 5;  // 4 channels each, 8 row-threads
    int c0 = ct * 128 + cg * 4;
    float sc[4][4], sh[4];
#pragma unroll
    for (int k = 0; k < 4; k++) {
        int c = c0 + k;
        float shk = 0.f;
#pragma unroll
        for (int jj = 0; jj < 4; jj++) {
            const float* gamma = jj == 0 ? g0 : jj == 1 ? g1 : jj == 2 ? g2 : g3;
            const float* beta = jj == 0 ? b0 : jj == 1 ? b1 : jj == 2 ? b2 : b3;
            float sum = branchAcc[jj * 512 + c];
            float sumsq = branchAcc[jj * 512 + 256 + c];
            float mean = sum * (1.f / 8192.f);
            float var = sumsq * (1.f / 8192.f) - mean * mean;
            float rs = rsqrtf(var + 1e-5f);
            float scv = gamma[c] * rs;
            sc[jj][k] = scv;
            shk += beta[c] - mean * scv;
        }
        sh[k] = shk;
    }
#pragma unroll
    for (int it = 0; it < 8; it++) {
        int ow = rt * 8 + it;
        size_t row = (size_t)b * 4096 + oh * 64 + ow;
        const unsigned short* p = ybr + row * OUTC + c0;
        float acc[4];
#pragma unroll
        for (int k = 0; k < 4; k++) acc[k] = sh[k];
#pragma unroll
        for (int jj = 0; jj < 4; jj++) {
            ushort4 u = *(const ushort4*)(p + (size_t)jj * M_ROWS * OUTC);
            acc[0] += bf2f(u.x) * sc[jj][0];
            acc[1] += bf2f(u.y) * sc[jj][1];
            acc[2] += bf2f(u.z) * sc[jj][2];
            acc[3] += bf2f(u.w) * sc[jj][3];
        }
#pragma unroll
        for (int k = 0; k < 4; k++) tile[ow][cg * 4 + k] = acc[k];
    }
    __syncthreads();
    int owq = t & 15, cp = t >> 4;
#pragma unroll
    for (int pass = 0; pass < 8; pass++) {
        int c = pass * 16 + cp;
        float4 v;
        v.x = tile[owq * 4 + 0][c];
        v.y = tile[owq * 4 + 1][c];
        v.z = tile[owq * 4 + 2][c];
        v.w = tile[owq * 4 + 3][c];
        *(float4*)(out + (((size_t)b * OUTC + ct * 128 + c) * 64 + oh) * 64 + owq * 4) = v;
    }
}

extern "C" void kernel_launch(void* const* d_in, const int* in_sizes, int n_in,
                              void* d_out, int out_size, void* d_ws, size_t ws_size,
                              hipStream_t stream) {
    char* ws = (char*)d_ws;
    size_t off = 0;
    auto alloc = [&](size_t bytes) {
        void* p = ws + off;
        off = (off + bytes + 255) & ~(size_t)255;
        return p;
    };
    unsigned short* ybr = (unsigned short*)alloc((size_t)4 * M_ROWS * OUTC * 2);  // 16.8 MB
    unsigned short* wt01 = (unsigned short*)alloc((size_t)442368 * 2);
    unsigned short* wtg2 = (unsigned short*)alloc((size_t)589824 * 2);
    unsigned short* wtg3 = (unsigned short*)alloc((size_t)1179648 * 2);
    unsigned short* xb2 = (unsigned short*)alloc((size_t)524288 * 2);
    unsigned short* xb3 = (unsigned short*)alloc((size_t)262144 * 2);
    unsigned short* T2 = (unsigned short*)alloc((size_t)2 * 1024 * 2304 * 2);  // 9.4 MB
    unsigned short* T3 = (unsigned short*)alloc((size_t)2 * 256 * 2304 * 2);   // 2.4 MB
    unsigned short* mapB01 = (unsigned short*)alloc((size_t)33800 * 192 * 2);  // 13 MB
    int* cnt32 = (int*)alloc((size_t)4 * 2 * HW * 4);                          // 0.5 MB
    float* branchAcc = (float*)alloc((size_t)4 * 512 * 4);                     // contiguous w/ cnt32
    unsigned short* list = (unsigned short*)alloc((size_t)4 * 2 * HW * MAXP * 2);  // 8 MB

    hipMemsetAsync(cnt32, 0, (size_t)4 * 2 * HW * 4 + 4 * 512 * 4, stream);

    fill_k<<<512, 256, 0, stream>>>(
        (const float*)d_in[1], (const float*)d_in[7], (const float*)d_in[13],
        (const float*)d_in[19],
        (const int*)d_in[2], (const int*)d_in[8], (const int*)d_in[14],
        (const int*)d_in[20], cnt32, list);
    prep2_k<<<3169 + 11712, 256, 0, stream>>>(
        (const float*)d_in[0], (const float*)d_in[6], cnt32, list, mapB01,
        (const float*)d_in[3], (const float*)d_in[9], (const float*)d_in[15],
        (const float*)d_in[21], wt01, wtg2, wtg3,
        (const float*)d_in[12], (const float*)d_in[18], xb2, xb3);
    mm_k<<<616, 256, 0, stream>>>(mapB01, wt01, xb2, xb3, wtg2, wtg3, T2, T3, ybr, branchAcc);
    asm_k<<<256, 256, 0, stream>>>(cnt32, list, T2, T3, ybr, branchAcc);
    out_k<<<dim3(64, 2, 2), 256, 0, stream>>>(ybr, branchAcc,
        (const float*)d_in[4], (const float*)d_in[10], (const float*)d_in[16],
        (const float*)d_in[22],
        (const float*)d_in[5], (const float*)d_in[11], (const float*)d_in[17],
        (const float*)d_in[23], (float*)d_out);
}

// Round 10
// 213.561 us; speedup vs baseline: 1.2923x; 1.2923x over previous
//
#include <hip/hip_runtime.h>

#define B 2
#define HW 16384
#define PADW 130
#define OUTC 256
#define M_ROWS 8192  // B*64*64
#define MAXP 32      // max points/cell tracked (lambda=1 Poisson; P(>32) ~ 0)

typedef short s16x8 __attribute__((ext_vector_type(8)));
typedef float f32x4 __attribute__((ext_vector_type(4)));

__device__ __forceinline__ unsigned short f2bf(float f) {
    union { float f; unsigned int u; } v; v.f = f;
    unsigned int u = v.u;
    return (unsigned short)((u + 0x7fffu + ((u >> 16) & 1u)) >> 16);
}
__device__ __forceinline__ float bf2f(unsigned short h) {
    union { unsigned int u; float f; } v; v.u = ((unsigned int)h) << 16;
    return v.f;
}

// async global->LDS, 16B per lane; LDS dest = wave-uniform base + lane*16
__device__ __forceinline__ void gl_lds16(const void* g, void* l) {
    __builtin_amdgcn_global_load_lds(
        (const __attribute__((address_space(1))) unsigned int*)g,
        (__attribute__((address_space(3))) unsigned int*)l, 16, 0, 0);
}

__device__ __forceinline__ void cell_of(const float* __restrict__ loc, int r, int& ix, int& iy) {
    float lx = loc[r * 2 + 0];
    float ly = loc[r * 2 + 1];
    lx = fminf(fmaxf(lx, -1.f), 1.f);
    ly = fminf(fmaxf(ly, -1.f), 1.f);
    ix = min(max((int)rintf(((lx + 1.f) * 0.5f) * 127.f), 0), 127);
    iy = min(max((int)rintf(((ly + 1.f) * 0.5f) * 127.f), 0), 127);
}

// Build per-cell token lists, all 4 branches. One thread per point (131072 total).
__global__ void fill_k(const float* __restrict__ l0, const float* __restrict__ l1,
                       const float* __restrict__ l2, const float* __restrict__ l3,
                       const int* __restrict__ i0, const int* __restrict__ i1,
                       const int* __restrict__ i2, const int* __restrict__ i3,
                       int* __restrict__ cnt32, unsigned short* __restrict__ list) {
    int p = blockIdx.x * 256 + threadIdx.x;
    int j = p >> 15, r = p & 32767;
    const float* loc = j == 0 ? l0 : j == 1 ? l1 : j == 2 ? l2 : l3;
    const int* idx = j == 0 ? i0 : j == 1 ? i1 : j == 2 ? i2 : i3;
    int ix, iy;
    cell_of(loc, r, ix, iy);
    int cidx = (((j << 1) + (r >> 14)) << 14) + iy * 128 + ix;
    int pos = atomicAdd(&cnt32[cidx], 1);
    if (pos < MAXP) list[cidx * MAXP + pos] = (unsigned short)idx[r];
}

// Merged prep: gather j0/j1 padded maps (blocks < 3169) + weight/x conversions (rest).
__global__ void prep2_k(const float* __restrict__ x0, const float* __restrict__ x1,
                        const int* __restrict__ cnt32, const unsigned short* __restrict__ list,
                        unsigned short* __restrict__ mapB01,
                        const float* __restrict__ w0, const float* __restrict__ w1,
                        const float* __restrict__ w2, const float* __restrict__ w3,
                        unsigned short* __restrict__ wt01,
                        unsigned short* __restrict__ wtg2, unsigned short* __restrict__ wtg3,
                        const float* __restrict__ x2, const float* __restrict__ x3,
                        unsigned short* __restrict__ xb2, unsigned short* __restrict__ xb3) {
    if (blockIdx.x >= 3169) {
        int e = (blockIdx.x - 3169) * 256 + threadIdx.x;
        if (e < 442368) {
            // direct-conv weights j0/j1: [co][(kh*3+kw)*C + ci]
            int j = e < 147456 ? 0 : 1;
            int local = j ? e - 147456 : e;
            const float* w = j ? w1 : w0;
            int lc = 6 + j, C = 1 << lc;
            int ci = local & (C - 1);
            int rest = local >> lc;
            int seg = rest % 9, co = rest / 9;
            int kh = seg / 3, kw = seg % 3;
            wt01[e] = f2bf(w[(((co * C) + ci) * 3 + kh) * 3 + kw]);
        } else if (e < 2211840) {
            // GEMM-B weights j2/j3: row (kk*256+co), col ci  -> [2304][C]
            int j = e < 1032192 ? 2 : 3;
            int local = j == 2 ? e - 442368 : e - 1032192;
            const float* w = j == 2 ? w2 : w3;
            int lc = 6 + j, C = 1 << lc;
            int ci = local & (C - 1);
            int nrow = local >> lc;
            int kk = nrow >> 8, co = nrow & 255;
            int kh = kk / 3, kw = kk % 3;
            unsigned short* dst = j == 2 ? wtg2 : wtg3;
            dst[local] = f2bf(w[(((co * C) + ci) * 3 + kh) * 3 + kw]);
        } else if (e < 2736128) {
            xb2[e - 2211840] = f2bf(x2[e - 2211840]);
        } else {
            xb3[e - 2736128] = f2bf(x3[e - 2736128]);
        }
        return;
    }
    // ---- gather j0/j1: wave-sliced cells, lanes_per_cell = C/8, 8 ch/lane (16B store)
    int W = (blockIdx.x * 256 + threadIdx.x) >> 6;
    if (W >= 12675) return;
    int lane = threadIdx.x & 63;
    int j = (W < 4225) ? 0 : 1;
    int base = j ? 4225 : 0;
    const float* x = j ? x1 : x0;
    const int C = 64 << j;
    const int ntok = 16384 >> (2 * j);
    int u = W - base;
    int cellLocal = (u << (3 - j)) + (lane >> (3 + j));  // < 33800
    int sub = lane & ((8 << j) - 1);
    int ch0 = sub * 8;
    int b = cellLocal / 16900;
    int cc = cellLocal - b * 16900;
    int py = cc / 130, px = cc - py * 130;
    unsigned short* dst = mapB01 + (size_t)33800 * (C - 64) + (size_t)cellLocal * C + ch0;
    float a0 = 0.f, a1 = 0.f, a2 = 0.f, a3 = 0.f, a4 = 0.f, a5 = 0.f, a6 = 0.f, a7 = 0.f;
    if (py >= 1 && py <= 128 && px >= 1 && px <= 128) {
        int cidx = (((j << 1) + b) << 14) + (py - 1) * 128 + (px - 1);
        int n = cnt32[cidx];
        float inv = 1.0f / ((float)n + 1e-6f);
        int nn = min(n, MAXP);
        const unsigned short* lst = list + (size_t)cidx * MAXP;
        for (int p = 0; p < nn; p++) {
            int tok = lst[p];
            const float* xr = x + ((size_t)b * ntok + tok) * C + ch0;
            float4 v0 = *(const float4*)xr;
            float4 v1 = *(const float4*)(xr + 4);
            a0 += v0.x; a1 += v0.y; a2 += v0.z; a3 += v0.w;
            a4 += v1.x; a5 += v1.y; a6 += v1.z; a7 += v1.w;
        }
        a0 *= inv; a1 *= inv; a2 *= inv; a3 *= inv;
        a4 *= inv; a5 *= inv; a6 *= inv; a7 *= inv;
    }
    uint4 o;
    o.x = (unsigned int)f2bf(a0) | ((unsigned int)f2bf(a1) << 16);
    o.y = (unsigned int)f2bf(a2) | ((unsigned int)f2bf(a3) << 16);
    o.z = (unsigned int)f2bf(a4) | ((unsigned int)f2bf(a5) << 16);
    o.w = (unsigned int)f2bf(a6) | ((unsigned int)f2bf(a7) << 16);
    *(uint4*)dst = o;
}

// Unified MFMA dispatch: j1 direct conv (128 blk, 36 steps), j3 token-GEMM (72 blk, 16),
// j2 token-GEMM (288 blk, 8), j0 direct conv (128 blk, 18). 128x128 tiles, 2x2 waves of
// 64x64, double-buffered LDS DMA staging (r5-proven). Conv blocks fuse exact BN stats.
__global__ __launch_bounds__(256) void mm_k(const unsigned short* __restrict__ mapB01,
                                            const unsigned short* __restrict__ wt01,
                                            const unsigned short* __restrict__ xb2,
                                            const unsigned short* __restrict__ xb3,
                                            const unsigned short* __restrict__ wtg2,
                                            const unsigned short* __restrict__ wtg3,
                                            unsigned short* __restrict__ T2,
                                            unsigned short* __restrict__ T3,
                                            unsigned short* __restrict__ ybr,
                                            float* __restrict__ branchAcc) {
    __shared__ unsigned short As[2][128][32];
    __shared__ unsigned short Bs[2][128][32];
    __shared__ float red_s[4][64], red_ss[4][64];
    const int t = threadIdx.x;
    const int lane = t & 63;
    const int w = t >> 6;
    const int wm = w >> 1, wn = w & 1;
    const int bx = blockIdx.x;

    bool isconv;
    int j, mt, nt, K, steps, C, bgem = 0;
    const unsigned short *Abase, *Bbase;
    if (bx < 128) {  // j1 conv, longest first
        isconv = true; j = 1; mt = bx & 63; nt = (bx >> 6) & 1;
        C = 128; K = 9 * C; steps = 36;
        Abase = mapB01 + (size_t)33800 * 64;
        Bbase = wt01 + (size_t)2304 * 64;
    } else if (bx < 200) {  // j3 GEMM
        isconv = false; j = 3; int r = bx - 128;
        bgem = r / 36; r %= 36; mt = r / 18; nt = r % 18;
        C = 512; K = C; steps = 16;
        Abase = xb3 + (size_t)bgem * 256 * 512;
        Bbase = wtg3;
    } else if (bx < 488) {  // j2 GEMM
        isconv = false; j = 2; int r = bx - 200;
        bgem = r / 144; r %= 144; mt = r / 18; nt = r % 18;
        C = 256; K = C; steps = 8;
        Abase = xb2 + (size_t)bgem * 1024 * 256;
        Bbase = wtg2;
    } else {  // j0 conv
        isconv = true; j = 0; int r = bx - 488; mt = r & 63; nt = (r >> 6) & 1;
        C = 64; K = 9 * C; steps = 18;
        Abase = mapB01;
        Bbase = wt01;
    }

    // staging sources: lane -> (row lr, 16B quarter lq); 2 A rows + 2 B rows per lane
    const int lr = lane >> 2, lq = lane & 3;
    const unsigned short* pA[2];
    const unsigned short* pB[2];
#pragma unroll
    for (int i = 0; i < 2; i++) {
        int r = w * 32 + i * 16 + lr;
        if (isconv) {
            int s = mt * 128 + r;
            int bb = s >> 12, rem = s & 4095, oh = rem >> 6, ow = rem & 63;
            pA[i] = Abase + (size_t)((bb * PADW + 2 * oh) * PADW + 2 * ow) * C + lq * 8;
        } else {
            pA[i] = Abase + (size_t)(mt * 128 + r) * K + lq * 8;
        }
        pB[i] = Bbase + (size_t)(nt * 128 + r) * K + lq * 8;
    }

    int ci0 = 0, kwv = 0, offA = 0, offB = 0;
    gl_lds16(pA[0], &As[0][w * 32][0]);
    gl_lds16(pA[1], &As[0][w * 32 + 16][0]);
    gl_lds16(pB[0], &Bs[0][w * 32][0]);
    gl_lds16(pB[1], &Bs[0][w * 32 + 16][0]);

    f32x4 acc[4][4];
#pragma unroll
    for (int mi = 0; mi < 4; mi++)
#pragma unroll
        for (int ni = 0; ni < 4; ni++) acc[mi][ni] = (f32x4){0.f, 0.f, 0.f, 0.f};

    const int r16 = lane & 15, kg = lane >> 4;
    int buf = 0;
    for (int s = 0; s < steps; s++) {
        offB += 32;
        if (isconv) {
            ci0 += 32; offA += 32;
            if (ci0 == C) {
                ci0 = 0; kwv++;
                if (kwv == 3) { kwv = 0; offA += (PADW - 3) * C; }
            }
        } else {
            offA += 32;
        }
        __syncthreads();  // drains prior prefetch (issued a full phase ago)
        if (s + 1 < steps) {
            int nb = buf ^ 1;
            gl_lds16(pA[0] + offA, &As[nb][w * 32][0]);
            gl_lds16(pA[1] + offA, &As[nb][w * 32 + 16][0]);
            gl_lds16(pB[0] + offB, &Bs[nb][w * 32][0]);
            gl_lds16(pB[1] + offB, &Bs[nb][w * 32 + 16][0]);
        }
        s16x8 a0 = *(const s16x8*)&As[buf][wm * 64 + 0 * 16 + r16][kg * 8];
        s16x8 a1 = *(const s16x8*)&As[buf][wm * 64 + 1 * 16 + r16][kg * 8];
        s16x8 a2 = *(const s16x8*)&As[buf][wm * 64 + 2 * 16 + r16][kg * 8];
        s16x8 a3 = *(const s16x8*)&As[buf][wm * 64 + 3 * 16 + r16][kg * 8];
        s16x8 b0 = *(const s16x8*)&Bs[buf][wn * 64 + 0 * 16 + r16][kg * 8];
        s16x8 b1 = *(const s16x8*)&Bs[buf][wn * 64 + 1 * 16 + r16][kg * 8];
        s16x8 b2 = *(const s16x8*)&Bs[buf][wn * 64 + 2 * 16 + r16][kg * 8];
        s16x8 b3 = *(const s16x8*)&Bs[buf][wn * 64 + 3 * 16 + r16][kg * 8];
        acc[0][0] = __builtin_amdgcn_mfma_f32_16x16x32_bf16(a0, b0, acc[0][0], 0, 0, 0);
        acc[0][1] = __builtin_amdgcn_mfma_f32_16x16x32_bf16(a0, b1, acc[0][1], 0, 0, 0);
        acc[0][2] = __builtin_amdgcn_mfma_f32_16x16x32_bf16(a0, b2, acc[0][2], 0, 0, 0);
        acc[0][3] = __builtin_amdgcn_mfma_f32_16x16x32_bf16(a0, b3, acc[0][3], 0, 0, 0);
        acc[1][0] = __builtin_amdgcn_mfma_f32_16x16x32_bf16(a1, b0, acc[1][0], 0, 0, 0);
        acc[1][1] = __builtin_amdgcn_mfma_f32_16x16x32_bf16(a1, b1, acc[1][1], 0, 0, 0);
        acc[1][2] = __builtin_amdgcn_mfma_f32_16x16x32_bf16(a1, b2, acc[1][2], 0, 0, 0);
        acc[1][3] = __builtin_amdgcn_mfma_f32_16x16x32_bf16(a1, b3, acc[1][3], 0, 0, 0);
        acc[2][0] = __builtin_amdgcn_mfma_f32_16x16x32_bf16(a2, b0, acc[2][0], 0, 0, 0);
        acc[2][1] = __builtin_amdgcn_mfma_f32_16x16x32_bf16(a2, b1, acc[2][1], 0, 0, 0);
        acc[2][2] = __builtin_amdgcn_mfma_f32_16x16x32_bf16(a2, b2, acc[2][2], 0, 0, 0);
        acc[2][3] = __builtin_amdgcn_mfma_f32_16x16x32_bf16(a2, b3, acc[2][3], 0, 0, 0);
        acc[3][0] = __builtin_amdgcn_mfma_f32_16x16x32_bf16(a3, b0, acc[3][0], 0, 0, 0);
        acc[3][1] = __builtin_amdgcn_mfma_f32_16x16x32_bf16(a3, b1, acc[3][1], 0, 0, 0);
        acc[3][2] = __builtin_amdgcn_mfma_f32_16x16x32_bf16(a3, b2, acc[3][2], 0, 0, 0);
        acc[3][3] = __builtin_amdgcn_mfma_f32_16x16x32_bf16(a3, b3, acc[3][3], 0, 0, 0);
        buf ^= 1;
    }

    // C/D layout: col = lane&15, row = (lane>>4)*4 + reg
    const int rg = lane >> 4, c16 = lane & 15;
    if (!isconv) {
        unsigned short* T = (j == 3) ? T3 + (size_t)bgem * 256 * 2304
                                     : T2 + (size_t)bgem * 1024 * 2304;
#pragma unroll
        for (int mi = 0; mi < 4; mi++)
#pragma unroll
            for (int ni = 0; ni < 4; ni++)
#pragma unroll
                for (int reg = 0; reg < 4; reg++) {
                    int row = mt * 128 + wm * 64 + mi * 16 + rg * 4 + reg;
                    int col = nt * 128 + wn * 64 + ni * 16 + c16;
                    T[(size_t)row * 2304 + col] = f2bf(acc[mi][ni][reg]);
                }
    } else {
#pragma unroll
        for (int mi = 0; mi < 4; mi++)
#pragma unroll
            for (int ni = 0; ni < 4; ni++)
#pragma unroll
                for (int reg = 0; reg < 4; reg++) {
                    int row = mt * 128 + wm * 64 + mi * 16 + rg * 4 + reg;
                    int col = nt * 128 + wn * 64 + ni * 16 + c16;
                    ybr[((size_t)j * M_ROWS + row) * OUTC + col] = f2bf(acc[mi][ni][reg]);
                }
        // fused exact channel stats (unsplit K -> each value computed once)
#pragma unroll
        for (int ni = 0; ni < 4; ni++) {
            float s = 0.f, ss = 0.f;
#pragma unroll
            for (int mi = 0; mi < 4; mi++)
#pragma unroll
                for (int reg = 0; reg < 4; reg++) {
                    float v = acc[mi][ni][reg];
                    s += v;
                    ss += v * v;
                }
            s += __shfl_xor(s, 16, 64);
            ss += __shfl_xor(ss, 16, 64);
            s += __shfl_xor(s, 32, 64);
            ss += __shfl_xor(ss, 32, 64);
            if (rg == 0) {
                red_s[w][ni * 16 + c16] = s;
                red_ss[w][ni * 16 + c16] = ss;
            }
        }
        __syncthreads();
        if (t < 128) {
            int col = t;
            int cwn = col >> 6, rem = col & 63;
            float s = red_s[cwn][rem] + red_s[cwn + 2][rem];
            float ss = red_ss[cwn][rem] + red_ss[cwn + 2][rem];
            int ch = nt * 128 + col;
            atomicAdd(&branchAcc[j * 512 + ch], s);
            atomicAdd(&branchAcc[j * 512 + 256 + ch], ss);
        }
    }
}

// Assemble j2/j3 outputs from token-GEMM T via tap gather; fused exact stats.
// 512 blocks (one branch each: bi<256 -> j2, else j3), 4 waves x 8 row-tasks.
// 3-phase ILP per task: 9 cnt loads -> 9 first-4-token list loads -> T loads.
__global__ __launch_bounds__(256) void asm_k(const int* __restrict__ cnt32,
                                             const unsigned short* __restrict__ list,
                                             const unsigned short* __restrict__ T2,
                                             const unsigned short* __restrict__ T3,
                                             unsigned short* __restrict__ ybr,
                                             float* __restrict__ branchAcc) {
    __shared__ float red[4][256];
    int t = threadIdx.x, lane = t & 63, w = t >> 6;
    int bi = blockIdx.x;               // 512
    int jj = bi >> 8;                  // 0: j2 (blocks 0..255), 1: j3
    int j = 2 + jj;
    int nj = jj ? 256 : 1024;
    const unsigned short* T = jj ? T3 : T2;
    int ch4 = lane << 2;
    float s0 = 0.f, s1 = 0.f, s2 = 0.f, s3 = 0.f;
    float q0 = 0.f, q1 = 0.f, q2 = 0.f, q3 = 0.f;

    for (int it = 0; it < 8; it++) {
        int srow = (bi & 255) * 32 + w * 8 + it;
        int b = srow >> 12, rem = srow & 4095, oh = rem >> 6, ow = rem & 63;
        // phase 1: all 9 cnt loads (independent)
        int narr[9], cidxs[9];
#pragma unroll
        for (int kh = 0; kh < 3; kh++)
#pragma unroll
            for (int kw = 0; kw < 3; kw++) {
                int tap = kh * 3 + kw;
                int iy = 2 * oh + kh - 1, ix = 2 * ow + kw - 1;
                bool ok = ((unsigned)iy < 128u) && ((unsigned)ix < 128u);
                int cidx = (((j << 1) + b) << 14) + (iy & 127) * 128 + (ix & 127);
                cidxs[tap] = cidx;
                narr[tap] = ok ? cnt32[cidx] : 0;
            }
        // phase 2: first-4-token ids per non-empty tap (independent)
        ushort4 l4[9];
#pragma unroll
        for (int tap = 0; tap < 9; tap++)
            if (narr[tap] > 0) l4[tap] = *(const ushort4*)(list + (size_t)cidxs[tap] * MAXP);
        // phase 3: T-row loads
        float a0 = 0.f, a1 = 0.f, a2 = 0.f, a3 = 0.f;
#pragma unroll
        for (int tap = 0; tap < 9; tap++) {
            int n = narr[tap];
            if (n == 0) continue;
            float wc = 1.0f / ((float)n + 1e-6f);
            int off = tap * 256 + ch4;
            unsigned short toks[4] = {(unsigned short)l4[tap].x, (unsigned short)l4[tap].y,
                                      (unsigned short)l4[tap].z, (unsigned short)l4[tap].w};
            float t0 = 0.f, t1 = 0.f, t2 = 0.f, t3 = 0.f;
            int nn = min(n, 4);
            for (int p = 0; p < nn; p++) {
                ushort4 u = *(const ushort4*)(T + ((size_t)(b * nj + toks[p]) * 2304 + off));
                t0 += bf2f(u.x); t1 += bf2f(u.y); t2 += bf2f(u.z); t3 += bf2f(u.w);
            }
            if (n > 4) {  // rare (P ~ 0.4%)
                int nm = min(n, MAXP);
                const unsigned short* lst = list + (size_t)cidxs[tap] * MAXP;
                for (int p = 4; p < nm; p++) {
                    int tok = lst[p];
                    ushort4 u = *(const ushort4*)(T + ((size_t)(b * nj + tok) * 2304 + off));
                    t0 += bf2f(u.x); t1 += bf2f(u.y); t2 += bf2f(u.z); t3 += bf2f(u.w);
                }
            }
            a0 += wc * t0; a1 += wc * t1; a2 += wc * t2; a3 += wc * t3;
        }
        ushort4 o;
        o.x = f2bf(a0); o.y = f2bf(a1); o.z = f2bf(a2); o.w = f2bf(a3);
        *(ushort4*)(ybr + ((size_t)j * M_ROWS + srow) * OUTC + ch4) = o;
        s0 += a0; s1 += a1; s2 += a2; s3 += a3;
        q0 += a0 * a0; q1 += a1 * a1; q2 += a2 * a2; q3 += a3 * a3;
    }
    // block reduce (single branch per block): sum pass then sumsq pass
    red[w][ch4 + 0] = s0; red[w][ch4 + 1] = s1; red[w][ch4 + 2] = s2; red[w][ch4 + 3] = s3;
    __syncthreads();
    float S = red[0][t] + red[1][t] + red[2][t] + red[3][t];
    __syncthreads();
    red[w][ch4 + 0] = q0; red[w][ch4 + 1] = q1; red[w][ch4 + 2] = q2; red[w][ch4 + 3] = q3;
    __syncthreads();
    float Q = red[0][t] + red[1][t] + red[2][t] + red[3][t];
    atomicAdd(&branchAcc[j * 512 + t], S);
    atomicAdd(&branchAcc[j * 512 + 256 + t], Q);
}

// fused: inline BN-fold from branchAcc + affine + 4-branch sum + NHWC->NCHW transpose
__global__ void out_k(const unsigned short* __restrict__ ybr, const float* __restrict__ branchAcc,
                      const float* __restrict__ g0, const float* __restrict__ g1,
                      const float* __restrict__ g2, const float* __restrict__ g3,
                      const float* __restrict__ b0, const float* __restrict__ b1,
                      const float* __restrict__ b2, const float* __restrict__ b3,
                      float* __restrict__ out) {
    __shared__ float tile[64][132];
    int oh = blockIdx.x, ct = blockIdx.y, b = blockIdx.z;  // 64, 2, 2
    int t = threadIdx.x;
    int cg = t & 31, rt = t >> 5;  // 4 channels each, 8 row-threads
    int c0 = ct * 128 + cg * 4;
    float sc[4][4], sh[4];
#pragma unroll
    for (int k = 0; k < 4; k++) {
        int c = c0 + k;
        float shk = 0.f;
#pragma unroll
        for (int jj = 0; jj < 4; jj++) {
            const float* gamma = jj == 0 ? g0 : jj == 1 ? g1 : jj == 2 ? g2 : g3;
            const float* beta = jj == 0 ? b0 : jj == 1 ? b1 : jj == 2 ? b2 : b3;
            float sum = branchAcc[jj * 512 + c];
            float sumsq = branchAcc[jj * 512 + 256 + c];
            float mean = sum * (1.f / 8192.f);
            float var = sumsq * (1.f / 8192.f) - mean * mean;
            float rs = rsqrtf(var + 1e-5f);
            float scv = gamma[c] * rs;
            sc[jj][k] = scv;
            shk += beta[c] - mean * scv;
        }
        sh[k] = shk;
    }
#pragma unroll
    for (int it = 0; it < 8; it++) {
        int ow = rt * 8 + it;
        size_t row = (size_t)b * 4096 + oh * 64 + ow;
        const unsigned short* p = ybr + row * OUTC + c0;
        float acc[4];
#pragma unroll
        for (int k = 0; k < 4; k++) acc[k] = sh[k];
#pragma unroll
        for (int jj = 0; jj < 4; jj++) {
            ushort4 u = *(const ushort4*)(p + (size_t)jj * M_ROWS * OUTC);
            acc[0] += bf2f(u.x) * sc[jj][0];
            acc[1] += bf2f(u.y) * sc[jj][1];
            acc[2] += bf2f(u.z) * sc[jj][2];
            acc[3] += bf2f(u.w) * sc[jj][3];
        }
#pragma unroll
        for (int k = 0; k < 4; k++) tile[ow][cg * 4 + k] = acc[k];
    }
    __syncthreads();
    int owq = t & 15, cp = t >> 4;
#pragma unroll
    for (int pass = 0; pass < 8; pass++) {
        int c = pass * 16 + cp;
        float4 v;
        v.x = tile[owq * 4 + 0][c];
        v.y = tile[owq * 4 + 1][c];
        v.z = tile[owq * 4 + 2][c];
        v.w = tile[owq * 4 + 3][c];
        *(float4*)(out + (((size_t)b * OUTC + ct * 128 + c) * 64 + oh) * 64 + owq * 4) = v;
    }
}

extern "C" void kernel_launch(void* const* d_in, const int* in_sizes, int n_in,
                              void* d_out, int out_size, void* d_ws, size_t ws_size,
                              hipStream_t stream) {
    char* ws = (char*)d_ws;
    size_t off = 0;
    auto alloc = [&](size_t bytes) {
        void* p = ws + off;
        off = (off + bytes + 255) & ~(size_t)255;
        return p;
    };
    unsigned short* ybr = (unsigned short*)alloc((size_t)4 * M_ROWS * OUTC * 2);  // 16.8 MB
    unsigned short* wt01 = (unsigned short*)alloc((size_t)442368 * 2);
    unsigned short* wtg2 = (unsigned short*)alloc((size_t)589824 * 2);
    unsigned short* wtg3 = (unsigned short*)alloc((size_t)1179648 * 2);
    unsigned short* xb2 = (unsigned short*)alloc((size_t)524288 * 2);
    unsigned short* xb3 = (unsigned short*)alloc((size_t)262144 * 2);
    unsigned short* T2 = (unsigned short*)alloc((size_t)2 * 1024 * 2304 * 2);  // 9.4 MB
    unsigned short* T3 = (unsigned short*)alloc((size_t)2 * 256 * 2304 * 2);   // 2.4 MB
    unsigned short* mapB01 = (unsigned short*)alloc((size_t)33800 * 192 * 2);  // 13 MB
    int* cnt32 = (int*)alloc((size_t)4 * 2 * HW * 4);                          // 0.5 MB
    float* branchAcc = (float*)alloc((size_t)4 * 512 * 4);                     // contiguous w/ cnt32
    unsigned short* list = (unsigned short*)alloc((size_t)4 * 2 * HW * MAXP * 2);  // 8 MB

    hipMemsetAsync(cnt32, 0, (size_t)4 * 2 * HW * 4 + 4 * 512 * 4, stream);

    fill_k<<<512, 256, 0, stream>>>(
        (const float*)d_in[1], (const float*)d_in[7], (const float*)d_in[13],
        (const float*)d_in[19],
        (const int*)d_in[2], (const int*)d_in[8], (const int*)d_in[14],
        (const int*)d_in[20], cnt32, list);
    prep2_k<<<3169 + 11712, 256, 0, stream>>>(
        (const float*)d_in[0], (const float*)d_in[6], cnt32, list, mapB01,
        (const float*)d_in[3], (const float*)d_in[9], (const float*)d_in[15],
        (const float*)d_in[21], wt01, wtg2, wtg3,
        (const float*)d_in[12], (const float*)d_in[18], xb2, xb3);
    mm_k<<<616, 256, 0, stream>>>(mapB01, wt01, xb2, xb3, wtg2, wtg3, T2, T3, ybr, branchAcc);
    asm_k<<<512, 256, 0, stream>>>(cnt32, list, T2, T3, ybr, branchAcc);
    out_k<<<dim3(64, 2, 2), 256, 0, stream>>>(ybr, branchAcc,
        (const float*)d_in[4], (const float*)d_in[10], (const float*)d_in[16],
        (const float*)d_in[22],
        (const float*)d_in[5], (const float*)d_in[11], (const float*)d_in[17],
        (const float*)d_in[23], (float*)d_out);
}

// Round 11
// 199.959 us; speedup vs baseline: 1.3802x; 1.0680x over previous
//
#include <hip/hip_runtime.h>

#define B 2
#define HW 16384
#define PADW 130
#define OUTC 256
#define M_ROWS 8192  // B*64*64
#define MAXP 32      // max points/cell tracked (lambda=1 Poisson; P(>32) ~ 0)

typedef short s16x8 __attribute__((ext_vector_type(8)));
typedef float f32x4 __attribute__((ext_vector_type(4)));

__device__ __forceinline__ unsigned short f2bf(float f) {
    union { float f; unsigned int u; } v; v.f = f;
    unsigned int u = v.u;
    return (unsigned short)((u + 0x7fffu + ((u >> 16) & 1u)) >> 16);
}
__device__ __forceinline__ float bf2f(unsigned short h) {
    union { unsigned int u; float f; } v; v.u = ((unsigned int)h) << 16;
    return v.f;
}

// async global->LDS, 16B per lane; LDS dest = wave-uniform base + lane*16
__device__ __forceinline__ void gl_lds16(const void* g, void* l) {
    __builtin_amdgcn_global_load_lds(
        (const __attribute__((address_space(1))) unsigned int*)g,
        (__attribute__((address_space(3))) unsigned int*)l, 16, 0, 0);
}

__device__ __forceinline__ void cell_of(const float* __restrict__ loc, int r, int& ix, int& iy) {
    float lx = loc[r * 2 + 0];
    float ly = loc[r * 2 + 1];
    lx = fminf(fmaxf(lx, -1.f), 1.f);
    ly = fminf(fmaxf(ly, -1.f), 1.f);
    ix = min(max((int)rintf(((lx + 1.f) * 0.5f) * 127.f), 0), 127);
    iy = min(max((int)rintf(((ly + 1.f) * 0.5f) * 127.f), 0), 127);
}

// Build per-cell token lists, all 4 branches. One thread per point (131072 total).
__global__ void fill_k(const float* __restrict__ l0, const float* __restrict__ l1,
                       const float* __restrict__ l2, const float* __restrict__ l3,
                       const int* __restrict__ i0, const int* __restrict__ i1,
                       const int* __restrict__ i2, const int* __restrict__ i3,
                       int* __restrict__ cnt32, unsigned short* __restrict__ list) {
    int p = blockIdx.x * 256 + threadIdx.x;
    int j = p >> 15, r = p & 32767;
    const float* loc = j == 0 ? l0 : j == 1 ? l1 : j == 2 ? l2 : l3;
    const int* idx = j == 0 ? i0 : j == 1 ? i1 : j == 2 ? i2 : i3;
    int ix, iy;
    cell_of(loc, r, ix, iy);
    int cidx = (((j << 1) + (r >> 14)) << 14) + iy * 128 + ix;
    int pos = atomicAdd(&cnt32[cidx], 1);
    if (pos < MAXP) list[cidx * MAXP + pos] = (unsigned short)idx[r];
}

// Merged prep: gather j0/j1 padded maps (blocks < 3169) + weight/x conversions (rest).
__global__ void prep2_k(const float* __restrict__ x0, const float* __restrict__ x1,
                        const int* __restrict__ cnt32, const unsigned short* __restrict__ list,
                        unsigned short* __restrict__ mapB01,
                        const float* __restrict__ w0, const float* __restrict__ w1,
                        const float* __restrict__ w2, const float* __restrict__ w3,
                        unsigned short* __restrict__ wt01,
                        unsigned short* __restrict__ wtg2, unsigned short* __restrict__ wtg3,
                        const float* __restrict__ x2, const float* __restrict__ x3,
                        unsigned short* __restrict__ xb2, unsigned short* __restrict__ xb3) {
    if (blockIdx.x >= 3169) {
        int e = (blockIdx.x - 3169) * 256 + threadIdx.x;
        if (e < 442368) {
            // direct-conv weights j0/j1: [co][(kh*3+kw)*C + ci]
            int j = e < 147456 ? 0 : 1;
            int local = j ? e - 147456 : e;
            const float* w = j ? w1 : w0;
            int lc = 6 + j, C = 1 << lc;
            int ci = local & (C - 1);
            int rest = local >> lc;
            int seg = rest % 9, co = rest / 9;
            int kh = seg / 3, kw = seg % 3;
            wt01[e] = f2bf(w[(((co * C) + ci) * 3 + kh) * 3 + kw]);
        } else if (e < 2211840) {
            // GEMM-B weights j2/j3: row (kk*256+co), col ci  -> [2304][C]
            int j = e < 1032192 ? 2 : 3;
            int local = j == 2 ? e - 442368 : e - 1032192;
            const float* w = j == 2 ? w2 : w3;
            int lc = 6 + j, C = 1 << lc;
            int ci = local & (C - 1);
            int nrow = local >> lc;
            int kk = nrow >> 8, co = nrow & 255;
            int kh = kk / 3, kw = kk % 3;
            unsigned short* dst = j == 2 ? wtg2 : wtg3;
            dst[local] = f2bf(w[(((co * C) + ci) * 3 + kh) * 3 + kw]);
        } else if (e < 2736128) {
            xb2[e - 2211840] = f2bf(x2[e - 2211840]);
        } else {
            xb3[e - 2736128] = f2bf(x3[e - 2736128]);
        }
        return;
    }
    // ---- gather j0/j1: wave-sliced cells, lanes_per_cell = C/8, 8 ch/lane (16B store)
    int W = (blockIdx.x * 256 + threadIdx.x) >> 6;
    if (W >= 12675) return;
    int lane = threadIdx.x & 63;
    int j = (W < 4225) ? 0 : 1;
    int base = j ? 4225 : 0;
    const float* x = j ? x1 : x0;
    const int C = 64 << j;
    const int ntok = 16384 >> (2 * j);
    int u = W - base;
    int cellLocal = (u << (3 - j)) + (lane >> (3 + j));  // < 33800
    int sub = lane & ((8 << j) - 1);
    int ch0 = sub * 8;
    int b = cellLocal / 16900;
    int cc = cellLocal - b * 16900;
    int py = cc / 130, px = cc - py * 130;
    unsigned short* dst = mapB01 + (size_t)33800 * (C - 64) + (size_t)cellLocal * C + ch0;
    float a0 = 0.f, a1 = 0.f, a2 = 0.f, a3 = 0.f, a4 = 0.f, a5 = 0.f, a6 = 0.f, a7 = 0.f;
    if (py >= 1 && py <= 128 && px >= 1 && px <= 128) {
        int cidx = (((j << 1) + b) << 14) + (py - 1) * 128 + (px - 1);
        // cnt and first-4 token list are independent loads -> issue both at once
        int n = cnt32[cidx];
        ushort4 l4 = *(const ushort4*)(list + (size_t)cidx * MAXP);
        float inv = 1.0f / ((float)n + 1e-6f);
        unsigned short toks[4] = {(unsigned short)l4.x, (unsigned short)l4.y,
                                  (unsigned short)l4.z, (unsigned short)l4.w};
        int nn = min(n, 4);
        for (int p = 0; p < nn; p++) {
            const float* xr = x + ((size_t)b * ntok + toks[p]) * C + ch0;
            float4 v0 = *(const float4*)xr;
            float4 v1 = *(const float4*)(xr + 4);
            a0 += v0.x; a1 += v0.y; a2 += v0.z; a3 += v0.w;
            a4 += v1.x; a5 += v1.y; a6 += v1.z; a7 += v1.w;
        }
        if (n > 4) {  // rare tail (P ~ 0.4%)
            int nm = min(n, MAXP);
            const unsigned short* lst = list + (size_t)cidx * MAXP;
            for (int p = 4; p < nm; p++) {
                int tok = lst[p];
                const float* xr = x + ((size_t)b * ntok + tok) * C + ch0;
                float4 v0 = *(const float4*)xr;
                float4 v1 = *(const float4*)(xr + 4);
                a0 += v0.x; a1 += v0.y; a2 += v0.z; a3 += v0.w;
                a4 += v1.x; a5 += v1.y; a6 += v1.z; a7 += v1.w;
            }
        }
        a0 *= inv; a1 *= inv; a2 *= inv; a3 *= inv;
        a4 *= inv; a5 *= inv; a6 *= inv; a7 *= inv;
    }
    uint4 o;
    o.x = (unsigned int)f2bf(a0) | ((unsigned int)f2bf(a1) << 16);
    o.y = (unsigned int)f2bf(a2) | ((unsigned int)f2bf(a3) << 16);
    o.z = (unsigned int)f2bf(a4) | ((unsigned int)f2bf(a5) << 16);
    o.w = (unsigned int)f2bf(a6) | ((unsigned int)f2bf(a7) << 16);
    *(uint4*)dst = o;
}

// Unified MFMA dispatch: j1 direct conv (128 blk, 36 steps), j3 token-GEMM (72 blk, 16),
// j2 token-GEMM (288 blk, 8), j0 direct conv (128 blk, 18). 128x128 tiles, 2x2 waves of
// 64x64, double-buffered LDS DMA staging (r5-proven). Conv blocks fuse exact BN stats.
__global__ __launch_bounds__(256) void mm_k(const unsigned short* __restrict__ mapB01,
                                            const unsigned short* __restrict__ wt01,
                                            const unsigned short* __restrict__ xb2,
                                            const unsigned short* __restrict__ xb3,
                                            const unsigned short* __restrict__ wtg2,
                                            const unsigned short* __restrict__ wtg3,
                                            unsigned short* __restrict__ T2,
                                            unsigned short* __restrict__ T3,
                                            unsigned short* __restrict__ ybr,
                                            float* __restrict__ branchAcc) {
    __shared__ unsigned short As[2][128][32];
    __shared__ unsigned short Bs[2][128][32];
    __shared__ float red_s[4][64], red_ss[4][64];
    const int t = threadIdx.x;
    const int lane = t & 63;
    const int w = t >> 6;
    const int wm = w >> 1, wn = w & 1;
    const int bx = blockIdx.x;

    bool isconv;
    int j, mt, nt, K, steps, C, bgem = 0;
    const unsigned short *Abase, *Bbase;
    if (bx < 128) {  // j1 conv, longest first
        isconv = true; j = 1; mt = bx & 63; nt = (bx >> 6) & 1;
        C = 128; K = 9 * C; steps = 36;
        Abase = mapB01 + (size_t)33800 * 64;
        Bbase = wt01 + (size_t)2304 * 64;
    } else if (bx < 200) {  // j3 GEMM
        isconv = false; j = 3; int r = bx - 128;
        bgem = r / 36; r %= 36; mt = r / 18; nt = r % 18;
        C = 512; K = C; steps = 16;
        Abase = xb3 + (size_t)bgem * 256 * 512;
        Bbase = wtg3;
    } else if (bx < 488) {  // j2 GEMM
        isconv = false; j = 2; int r = bx - 200;
        bgem = r / 144; r %= 144; mt = r / 18; nt = r % 18;
        C = 256; K = C; steps = 8;
        Abase = xb2 + (size_t)bgem * 1024 * 256;
        Bbase = wtg2;
    } else {  // j0 conv
        isconv = true; j = 0; int r = bx - 488; mt = r & 63; nt = (r >> 6) & 1;
        C = 64; K = 9 * C; steps = 18;
        Abase = mapB01;
        Bbase = wt01;
    }

    // staging sources: lane -> (row lr, 16B quarter lq); 2 A rows + 2 B rows per lane
    const int lr = lane >> 2, lq = lane & 3;
    const unsigned short* pA[2];
    const unsigned short* pB[2];
#pragma unroll
    for (int i = 0; i < 2; i++) {
        int r = w * 32 + i * 16 + lr;
        if (isconv) {
            int s = mt * 128 + r;
            int bb = s >> 12, rem = s & 4095, oh = rem >> 6, ow = rem & 63;
            pA[i] = Abase + (size_t)((bb * PADW + 2 * oh) * PADW + 2 * ow) * C + lq * 8;
        } else {
            pA[i] = Abase + (size_t)(mt * 128 + r) * K + lq * 8;
        }
        pB[i] = Bbase + (size_t)(nt * 128 + r) * K + lq * 8;
    }

    int ci0 = 0, kwv = 0, offA = 0, offB = 0;
    gl_lds16(pA[0], &As[0][w * 32][0]);
    gl_lds16(pA[1], &As[0][w * 32 + 16][0]);
    gl_lds16(pB[0], &Bs[0][w * 32][0]);
    gl_lds16(pB[1], &Bs[0][w * 32 + 16][0]);

    f32x4 acc[4][4];
#pragma unroll
    for (int mi = 0; mi < 4; mi++)
#pragma unroll
        for (int ni = 0; ni < 4; ni++) acc[mi][ni] = (f32x4){0.f, 0.f, 0.f, 0.f};

    const int r16 = lane & 15, kg = lane >> 4;
    int buf = 0;
    for (int s = 0; s < steps; s++) {
        offB += 32;
        if (isconv) {
            ci0 += 32; offA += 32;
            if (ci0 == C) {
                ci0 = 0; kwv++;
                if (kwv == 3) { kwv = 0; offA += (PADW - 3) * C; }
            }
        } else {
            offA += 32;
        }
        __syncthreads();  // drains prior prefetch (issued a full phase ago)
        if (s + 1 < steps) {
            int nb = buf ^ 1;
            gl_lds16(pA[0] + offA, &As[nb][w * 32][0]);
            gl_lds16(pA[1] + offA, &As[nb][w * 32 + 16][0]);
            gl_lds16(pB[0] + offB, &Bs[nb][w * 32][0]);
            gl_lds16(pB[1] + offB, &Bs[nb][w * 32 + 16][0]);
        }
        s16x8 a0 = *(const s16x8*)&As[buf][wm * 64 + 0 * 16 + r16][kg * 8];
        s16x8 a1 = *(const s16x8*)&As[buf][wm * 64 + 1 * 16 + r16][kg * 8];
        s16x8 a2 = *(const s16x8*)&As[buf][wm * 64 + 2 * 16 + r16][kg * 8];
        s16x8 a3 = *(const s16x8*)&As[buf][wm * 64 + 3 * 16 + r16][kg * 8];
        s16x8 b0 = *(const s16x8*)&Bs[buf][wn * 64 + 0 * 16 + r16][kg * 8];
        s16x8 b1 = *(const s16x8*)&Bs[buf][wn * 64 + 1 * 16 + r16][kg * 8];
        s16x8 b2 = *(const s16x8*)&Bs[buf][wn * 64 + 2 * 16 + r16][kg * 8];
        s16x8 b3 = *(const s16x8*)&Bs[buf][wn * 64 + 3 * 16 + r16][kg * 8];
        acc[0][0] = __builtin_amdgcn_mfma_f32_16x16x32_bf16(a0, b0, acc[0][0], 0, 0, 0);
        acc[0][1] = __builtin_amdgcn_mfma_f32_16x16x32_bf16(a0, b1, acc[0][1], 0, 0, 0);
        acc[0][2] = __builtin_amdgcn_mfma_f32_16x16x32_bf16(a0, b2, acc[0][2], 0, 0, 0);
        acc[0][3] = __builtin_amdgcn_mfma_f32_16x16x32_bf16(a0, b3, acc[0][3], 0, 0, 0);
        acc[1][0] = __builtin_amdgcn_mfma_f32_16x16x32_bf16(a1, b0, acc[1][0], 0, 0, 0);
        acc[1][1] = __builtin_amdgcn_mfma_f32_16x16x32_bf16(a1, b1, acc[1][1], 0, 0, 0);
        acc[1][2] = __builtin_amdgcn_mfma_f32_16x16x32_bf16(a1, b2, acc[1][2], 0, 0, 0);
        acc[1][3] = __builtin_amdgcn_mfma_f32_16x16x32_bf16(a1, b3, acc[1][3], 0, 0, 0);
        acc[2][0] = __builtin_amdgcn_mfma_f32_16x16x32_bf16(a2, b0, acc[2][0], 0, 0, 0);
        acc[2][1] = __builtin_amdgcn_mfma_f32_16x16x32_bf16(a2, b1, acc[2][1], 0, 0, 0);
        acc[2][2] = __builtin_amdgcn_mfma_f32_16x16x32_bf16(a2, b2, acc[2][2], 0, 0, 0);
        acc[2][3] = __builtin_amdgcn_mfma_f32_16x16x32_bf16(a2, b3, acc[2][3], 0, 0, 0);
        acc[3][0] = __builtin_amdgcn_mfma_f32_16x16x32_bf16(a3, b0, acc[3][0], 0, 0, 0);
        acc[3][1] = __builtin_amdgcn_mfma_f32_16x16x32_bf16(a3, b1, acc[3][1], 0, 0, 0);
        acc[3][2] = __builtin_amdgcn_mfma_f32_16x16x32_bf16(a3, b2, acc[3][2], 0, 0, 0);
        acc[3][3] = __builtin_amdgcn_mfma_f32_16x16x32_bf16(a3, b3, acc[3][3], 0, 0, 0);
        buf ^= 1;
    }

    // C/D layout: col = lane&15, row = (lane>>4)*4 + reg
    const int rg = lane >> 4, c16 = lane & 15;
    if (!isconv) {
        unsigned short* T = (j == 3) ? T3 + (size_t)bgem * 256 * 2304
                                     : T2 + (size_t)bgem * 1024 * 2304;
#pragma unroll
        for (int mi = 0; mi < 4; mi++)
#pragma unroll
            for (int ni = 0; ni < 4; ni++)
#pragma unroll
                for (int reg = 0; reg < 4; reg++) {
                    int row = mt * 128 + wm * 64 + mi * 16 + rg * 4 + reg;
                    int col = nt * 128 + wn * 64 + ni * 16 + c16;
                    T[(size_t)row * 2304 + col] = f2bf(acc[mi][ni][reg]);
                }
    } else {
#pragma unroll
        for (int mi = 0; mi < 4; mi++)
#pragma unroll
            for (int ni = 0; ni < 4; ni++)
#pragma unroll
                for (int reg = 0; reg < 4; reg++) {
                    int row = mt * 128 + wm * 64 + mi * 16 + rg * 4 + reg;
                    int col = nt * 128 + wn * 64 + ni * 16 + c16;
                    ybr[((size_t)j * M_ROWS + row) * OUTC + col] = f2bf(acc[mi][ni][reg]);
                }
        // fused exact channel stats (unsplit K -> each value computed once)
#pragma unroll
        for (int ni = 0; ni < 4; ni++) {
            float s = 0.f, ss = 0.f;
#pragma unroll
            for (int mi = 0; mi < 4; mi++)
#pragma unroll
                for (int reg = 0; reg < 4; reg++) {
                    float v = acc[mi][ni][reg];
                    s += v;
                    ss += v * v;
                }
            s += __shfl_xor(s, 16, 64);
            ss += __shfl_xor(ss, 16, 64);
            s += __shfl_xor(s, 32, 64);
            ss += __shfl_xor(ss, 32, 64);
            if (rg == 0) {
                red_s[w][ni * 16 + c16] = s;
                red_ss[w][ni * 16 + c16] = ss;
            }
        }
        __syncthreads();
        if (t < 128) {
            int col = t;
            int cwn = col >> 6, rem = col & 63;
            float s = red_s[cwn][rem] + red_s[cwn + 2][rem];
            float ss = red_ss[cwn][rem] + red_ss[cwn + 2][rem];
            int ch = nt * 128 + col;
            atomicAdd(&branchAcc[j * 512 + ch], s);
            atomicAdd(&branchAcc[j * 512 + 256 + ch], ss);
        }
    }
}

// Assemble j2/j3 outputs from token-GEMM T via tap gather; fused exact stats.
// 1024 blocks (bi<512 -> j2, else j3), 4 waves x 4 row-tasks.
// 2-phase ILP per task: {9 cnt + 9 list} loads together (independent) -> T loads.
__global__ __launch_bounds__(256) void asm_k(const int* __restrict__ cnt32,
                                             const unsigned short* __restrict__ list,
                                             const unsigned short* __restrict__ T2,
                                             const unsigned short* __restrict__ T3,
                                             unsigned short* __restrict__ ybr,
                                             float* __restrict__ branchAcc) {
    __shared__ float red[4][256];
    int t = threadIdx.x, lane = t & 63, w = t >> 6;
    int bi = blockIdx.x;               // 1024
    int jj = bi >> 9;                  // 0: j2 (blocks 0..511), 1: j3
    int j = 2 + jj;
    int nj = jj ? 256 : 1024;
    const unsigned short* T = jj ? T3 : T2;
    int ch4 = lane << 2;
    float s0 = 0.f, s1 = 0.f, s2 = 0.f, s3 = 0.f;
    float q0 = 0.f, q1 = 0.f, q2 = 0.f, q3 = 0.f;

    for (int it = 0; it < 4; it++) {
        int srow = (bi & 511) * 16 + w * 4 + it;
        int b = srow >> 12, rem = srow & 4095, oh = rem >> 6, ow = rem & 63;
        // phase 1: all 9 cnt loads AND all 9 first-4-token list loads (fully independent)
        int narr[9], cidxs[9];
        ushort4 l4[9];
#pragma unroll
        for (int kh = 0; kh < 3; kh++)
#pragma unroll
            for (int kw = 0; kw < 3; kw++) {
                int tap = kh * 3 + kw;
                int iy = 2 * oh + kh - 1, ix = 2 * ow + kw - 1;
                bool ok = ((unsigned)iy < 128u) && ((unsigned)ix < 128u);
                int cidx = (((j << 1) + b) << 14) + (iy & 127) * 128 + (ix & 127);
                cidxs[tap] = cidx;
                int n = cnt32[cidx];                                     // indep load
                l4[tap] = *(const ushort4*)(list + (size_t)cidx * MAXP); // indep load
                narr[tap] = ok ? n : 0;
            }
        // phase 2: T-row loads
        float a0 = 0.f, a1 = 0.f, a2 = 0.f, a3 = 0.f;
#pragma unroll
        for (int tap = 0; tap < 9; tap++) {
            int n = narr[tap];
            if (n == 0) continue;
            float wc = 1.0f / ((float)n + 1e-6f);
            int off = tap * 256 + ch4;
            unsigned short toks[4] = {(unsigned short)l4[tap].x, (unsigned short)l4[tap].y,
                                      (unsigned short)l4[tap].z, (unsigned short)l4[tap].w};
            float t0 = 0.f, t1 = 0.f, t2 = 0.f, t3 = 0.f;
            int nn = min(n, 4);
            for (int p = 0; p < nn; p++) {
                ushort4 u = *(const ushort4*)(T + ((size_t)(b * nj + toks[p]) * 2304 + off));
                t0 += bf2f(u.x); t1 += bf2f(u.y); t2 += bf2f(u.z); t3 += bf2f(u.w);
            }
            if (n > 4) {  // rare (P ~ 0.4%)
                int nm = min(n, MAXP);
                const unsigned short* lst = list + (size_t)cidxs[tap] * MAXP;
                for (int p = 4; p < nm; p++) {
                    int tok = lst[p];
                    ushort4 u = *(const ushort4*)(T + ((size_t)(b * nj + tok) * 2304 + off));
                    t0 += bf2f(u.x); t1 += bf2f(u.y); t2 += bf2f(u.z); t3 += bf2f(u.w);
                }
            }
            a0 += wc * t0; a1 += wc * t1; a2 += wc * t2; a3 += wc * t3;
        }
        ushort4 o;
        o.x = f2bf(a0); o.y = f2bf(a1); o.z = f2bf(a2); o.w = f2bf(a3);
        *(ushort4*)(ybr + ((size_t)j * M_ROWS + srow) * OUTC + ch4) = o;
        s0 += a0; s1 += a1; s2 += a2; s3 += a3;
        q0 += a0 * a0; q1 += a1 * a1; q2 += a2 * a2; q3 += a3 * a3;
    }
    // block reduce (single branch per block): sum pass then sumsq pass
    red[w][ch4 + 0] = s0; red[w][ch4 + 1] = s1; red[w][ch4 + 2] = s2; red[w][ch4 + 3] = s3;
    __syncthreads();
    float S = red[0][t] + red[1][t] + red[2][t] + red[3][t];
    __syncthreads();
    red[w][ch4 + 0] = q0; red[w][ch4 + 1] = q1; red[w][ch4 + 2] = q2; red[w][ch4 + 3] = q3;
    __syncthreads();
    float Q = red[0][t] + red[1][t] + red[2][t] + red[3][t];
    atomicAdd(&branchAcc[j * 512 + t], S);
    atomicAdd(&branchAcc[j * 512 + 256 + t], Q);
}

// fused: inline BN-fold from branchAcc + affine + 4-branch sum + NHWC->NCHW transpose
__global__ void out_k(const unsigned short* __restrict__ ybr, const float* __restrict__ branchAcc,
                      const float* __restrict__ g0, const float* __restrict__ g1,
                      const float* __restrict__ g2, const float* __restrict__ g3,
                      const float* __restrict__ b0, const float* __restrict__ b1,
                      const float* __restrict__ b2, const float* __restrict__ b3,
                      float* __restrict__ out) {
    __shared__ float tile[64][132];
    int oh = blockIdx.x, ct = blockIdx.y, b = blockIdx.z;  // 64, 2, 2
    int t = threadIdx.x;
    int cg = t & 31, rt = t >> 5;  // 4 channels each, 8 row-threads
    int c0 = ct * 128 + cg * 4;
    float sc[4][4], sh[4];
#pragma unroll
    for (int k = 0; k < 4; k++) {
        int c = c0 + k;
        float shk = 0.f;
#pragma unroll
        for (int jj = 0; jj < 4; jj++) {
            const float* gamma = jj == 0 ? g0 : jj == 1 ? g1 : jj == 2 ? g2 : g3;
            const float* beta = jj == 0 ? b0 : jj == 1 ? b1 : jj == 2 ? b2 : b3;
            float sum = branchAcc[jj * 512 + c];
            float sumsq = branchAcc[jj * 512 + 256 + c];
            float mean = sum * (1.f / 8192.f);
            float var = sumsq * (1.f / 8192.f) - mean * mean;
            float rs = rsqrtf(var + 1e-5f);
            float scv = gamma[c] * rs;
            sc[jj][k] = scv;
            shk += beta[c] - mean * scv;
        }
        sh[k] = shk;
    }
#pragma unroll
    for (int it = 0; it < 8; it++) {
        int ow = rt * 8 + it;
        size_t row = (size_t)b * 4096 + oh * 64 + ow;
        const unsigned short* p = ybr + row * OUTC + c0;
        float acc[4];
#pragma unroll
        for (int k = 0; k < 4; k++) acc[k] = sh[k];
#pragma unroll
        for (int jj = 0; jj < 4; jj++) {
            ushort4 u = *(const ushort4*)(p + (size_t)jj * M_ROWS * OUTC);
            acc[0] += bf2f(u.x) * sc[jj][0];
            acc[1] += bf2f(u.y) * sc[jj][1];
            acc[2] += bf2f(u.z) * sc[jj][2];
            acc[3] += bf2f(u.w) * sc[jj][3];
        }
#pragma unroll
        for (int k = 0; k < 4; k++) tile[ow][cg * 4 + k] = acc[k];
    }
    __syncthreads();
    int owq = t & 15, cp = t >> 4;
#pragma unroll
    for (int pass = 0; pass < 8; pass++) {
        int c = pass * 16 + cp;
        float4 v;
        v.x = tile[owq * 4 + 0][c];
        v.y = tile[owq * 4 + 1][c];
        v.z = tile[owq * 4 + 2][c];
        v.w = tile[owq * 4 + 3][c];
        *(float4*)(out + (((size_t)b * OUTC + ct * 128 + c) * 64 + oh) * 64 + owq * 4) = v;
    }
}

extern "C" void kernel_launch(void* const* d_in, const int* in_sizes, int n_in,
                              void* d_out, int out_size, void* d_ws, size_t ws_size,
                              hipStream_t stream) {
    char* ws = (char*)d_ws;
    size_t off = 0;
    auto alloc = [&](size_t bytes) {
        void* p = ws + off;
        off = (off + bytes + 255) & ~(size_t)255;
        return p;
    };
    unsigned short* ybr = (unsigned short*)alloc((size_t)4 * M_ROWS * OUTC * 2);  // 16.8 MB
    unsigned short* wt01 = (unsigned short*)alloc((size_t)442368 * 2);
    unsigned short* wtg2 = (unsigned short*)alloc((size_t)589824 * 2);
    unsigned short* wtg3 = (unsigned short*)alloc((size_t)1179648 * 2);
    unsigned short* xb2 = (unsigned short*)alloc((size_t)524288 * 2);
    unsigned short* xb3 = (unsigned short*)alloc((size_t)262144 * 2);
    unsigned short* T2 = (unsigned short*)alloc((size_t)2 * 1024 * 2304 * 2);  // 9.4 MB
    unsigned short* T3 = (unsigned short*)alloc((size_t)2 * 256 * 2304 * 2);   // 2.4 MB
    unsigned short* mapB01 = (unsigned short*)alloc((size_t)33800 * 192 * 2);  // 13 MB
    int* cnt32 = (int*)alloc((size_t)4 * 2 * HW * 4);                          // 0.5 MB
    float* branchAcc = (float*)alloc((size_t)4 * 512 * 4);                     // contiguous w/ cnt32
    unsigned short* list = (unsigned short*)alloc((size_t)4 * 2 * HW * MAXP * 2);  // 8 MB

    hipMemsetAsync(cnt32, 0, (size_t)4 * 2 * HW * 4 + 4 * 512 * 4, stream);

    fill_k<<<512, 256, 0, stream>>>(
        (const float*)d_in[1], (const float*)d_in[7], (const float*)d_in[13],
        (const float*)d_in[19],
        (const int*)d_in[2], (const int*)d_in[8], (const int*)d_in[14],
        (const int*)d_in[20], cnt32, list);
    prep2_k<<<3169 + 11712, 256, 0, stream>>>(
        (const float*)d_in[0], (const float*)d_in[6], cnt32, list, mapB01,
        (const float*)d_in[3], (const float*)d_in[9], (const float*)d_in[15],
        (const float*)d_in[21], wt01, wtg2, wtg3,
        (const float*)d_in[12], (const float*)d_in[18], xb2, xb3);
    mm_k<<<616, 256, 0, stream>>>(mapB01, wt01, xb2, xb3, wtg2, wtg3, T2, T3, ybr, branchAcc);
    asm_k<<<1024, 256, 0, stream>>>(cnt32, list, T2, T3, ybr, branchAcc);
    out_k<<<dim3(64, 2, 2), 256, 0, stream>>>(ybr, branchAcc,
        (const float*)d_in[4], (const float*)d_in[10], (const float*)d_in[16],
        (const float*)d_in[22],
        (const float*)d_in[5], (const float*)d_in[11], (const float*)d_in[17],
        (const float*)d_in[23], (float*)d_out);
}